// Round 14
// baseline (861.172 us; speedup 1.0000x reference)
//
#include <hip/hip_runtime.h>
#include <math.h>

#define TB    720
#define NI    16
#define NH    128
#define NG    512
#define PRED  96
#define CHUNK 90          // 720 = 8 * 90

typedef _Float16 h2    __attribute__((ext_vector_type(2)));
typedef _Float16 f16x4 __attribute__((ext_vector_type(4)));
typedef _Float16 f16x8 __attribute__((ext_vector_type(8)));
typedef float    f32x4 __attribute__((ext_vector_type(4)));

#define LOG2E  1.4426950408889634f
#define LOG2E2 2.8853900817779268f

__device__ __forceinline__ float rcpf_(float v) {
#if __has_builtin(__builtin_amdgcn_rcpf)
    return __builtin_amdgcn_rcpf(v);
#else
    return 1.0f / v;
#endif
}
__device__ __forceinline__ float ex2(float v) {
#if __has_builtin(__builtin_amdgcn_exp2f)
    return __builtin_amdgcn_exp2f(v);
#else
    return exp2f(v);
#endif
}
__device__ __forceinline__ float sigf(float v)   { return rcpf_(1.0f + __expf(-v)); }
__device__ __forceinline__ float tanhf_(float v) { return 1.0f - 2.0f * rcpf_(1.0f + __expf(2.0f * v)); }

__device__ __forceinline__ unsigned int packf16(float a, float b) {
    h2 p; p.x = (_Float16)a; p.y = (_Float16)b;
    return __builtin_bit_cast(unsigned int, p);
}
__device__ __forceinline__ float2 unpackf16(unsigned int u) {
    h2 p = __builtin_bit_cast(h2, u);
    return make_float2((float)p.x, (float)p.y);
}
__device__ __forceinline__ float fdot2f(unsigned int a, unsigned int b, float c) {
#if __has_builtin(__builtin_amdgcn_fdot2)
    return __builtin_amdgcn_fdot2(__builtin_bit_cast(h2, a), __builtin_bit_cast(h2, b), c, false);
#else
    h2 x = __builtin_bit_cast(h2, a), y = __builtin_bit_cast(h2, b);
    return c + (float)x.x * (float)y.x + (float)x.y * (float)y.y;
#endif
}

// A/B frag split-half k layout (verified R9-R13); scaled variant for exp2 gates
__device__ __forceinline__ f16x8 mk8s(const float* p, float s) {
    f16x8 v;
    v[0] = (_Float16)(p[0]  * s); v[1] = (_Float16)(p[1]  * s);
    v[2] = (_Float16)(p[2]  * s); v[3] = (_Float16)(p[3]  * s);
    v[4] = (_Float16)(p[16] * s); v[5] = (_Float16)(p[17] * s);
    v[6] = (_Float16)(p[18] * s); v[7] = (_Float16)(p[19] * s);
    return v;
}
__device__ __forceinline__ f32x4 MFMA(f16x8 a, f16x8 b, f32x4 c) {
    return __builtin_amdgcn_mfma_f32_16x16x32_f16(a, b, c, 0, 0, 0);
}

// ---------------- encoder (MFMA, 512thr; exp2-prescaled gates, paired rcp) ----------------
// R13 structure. Weights prescaled: sigma-gate rows x log2e, g-gate rows x 2log2e,
// so CELL uses v_exp (2^x) directly and 3 rcp/cell (paired) instead of 5.
__global__ __launch_bounds__(512, 1)
void enc_kernel(const float* __restrict__ x,
                const float* __restrict__ Wih_f, const float* __restrict__ Whh_f, const float* __restrict__ b_f,
                const float* __restrict__ Wih_b, const float* __restrict__ Whh_b, const float* __restrict__ b_b,
                float* __restrict__ st)   // st[b][dir][{h,c}][NH]
{
    __shared__ _Float16 hbuf0[16 * NH];        // 4KB frag-major
    __shared__ _Float16 hbuf1[16 * NH];
    __shared__ unsigned int xsh[CHUNK * 128];  // 46KB

    const int blk = blockIdx.x;
    const int dir = blk & 1;
    const int b0  = (blk >> 1) << 4;
    const int t   = threadIdx.x;
    const int wv  = t >> 6;
    const int l   = t & 63;
    const int lr  = l & 15;
    const int lk  = l >> 4;

    const float* Wih = dir ? Wih_b : Wih_f;
    const float* Whh = dir ? Whh_b : Whh_f;
    const float* bv  = dir ? b_b   : b_f;

    const int mt0 = wv * 4, mt1 = wv * 4 + 1, mt2 = wv * 4 + 2, mt3 = wv * 4 + 3;
    const int R0 = mt0 * 16 + lr, R1 = mt1 * 16 + lr, R2 = mt2 * 16 + lr, R3 = mt3 * 16 + lr;
    const int or0 = (R0 & 3) * 128 + (R0 >> 2);
    const int or1 = (R1 & 3) * 128 + (R1 >> 2);
    const int or2 = (R2 & 3) * 128 + (R2 >> 2);
    const int or3 = (R3 & 3) * 128 + (R3 >> 2);
    const float s0 = ((or0 >> 7) == 2) ? LOG2E2 : LOG2E;
    const float s1 = ((or1 >> 7) == 2) ? LOG2E2 : LOG2E;
    const float s2 = ((or2 >> 7) == 2) ? LOG2E2 : LOG2E;
    const float s3 = ((or3 >> 7) == 2) ? LOG2E2 : LOG2E;
    const float* p0 = Whh + (size_t)or0 * NH + lk * 4;
    const float* p1 = Whh + (size_t)or1 * NH + lk * 4;
    const float* p2 = Whh + (size_t)or2 * NH + lk * 4;
    const float* p3 = Whh + (size_t)or3 * NH + lk * 4;
    f16x8 w0_0 = mk8s(p0, s0), w0_1 = mk8s(p0 + 32, s0), w0_2 = mk8s(p0 + 64, s0), w0_3 = mk8s(p0 + 96, s0);
    f16x8 w1_0 = mk8s(p1, s1), w1_1 = mk8s(p1 + 32, s1), w1_2 = mk8s(p1 + 64, s1), w1_3 = mk8s(p1 + 96, s1);
    f16x8 w2_0 = mk8s(p2, s2), w2_1 = mk8s(p2 + 32, s2), w2_2 = mk8s(p2 + 64, s2), w2_3 = mk8s(p2 + 96, s2);
    f16x8 w3_0 = mk8s(p3, s3), w3_1 = mk8s(p3 + 32, s3), w3_2 = mk8s(p3 + 64, s3), w3_3 = mk8s(p3 + 96, s3);

    f16x8 ax0, ax1, ax2, ax3;
#define MKAXR(DST, OR, SC) { \
    const float* xr_ = Wih + (size_t)(OR) * NI + lk * 4; \
    DST[0] = (_Float16)(xr_[0] * (SC)); DST[1] = (_Float16)(xr_[1] * (SC)); \
    DST[2] = (_Float16)(xr_[2] * (SC)); DST[3] = (_Float16)(xr_[3] * (SC)); \
    DST[4] = (_Float16)(bv[(OR)] * (SC)); \
    DST[5] = (_Float16)0.f; DST[6] = (_Float16)0.f; DST[7] = (_Float16)0.f; }
    MKAXR(ax0, or0, s0) MKAXR(ax1, or1, s1) MKAXR(ax2, or2, s2) MKAXR(ax3, or3, s3)
#undef MKAXR

    const int d0 = mt0 * 4 + lk, d1 = mt1 * 4 + lk, d2 = mt2 * 4 + lk, d3 = mt3 * 4 + lk;

    ((unsigned int*)hbuf0)[t] = 0u;
    ((unsigned int*)hbuf0)[t + 512] = 0u;
    float cs0 = 0.f, cs1 = 0.f, cs2 = 0.f, cs3 = 0.f;

    const int hro0 = 0 * 1024 + lk * 256 + lr * 16;
    const int hro1 = 1 * 1024 + lk * 256 + lr * 16;
    const int hro2 = 2 * 1024 + lk * 256 + lr * 16;
    const int hro3 = 3 * 1024 + lk * 256 + lr * 16;
#define CWB(D) ((((D) >> 5) * 1024) + ((((D) & 15) >> 2) * 256) + lr * 16 + (((((D) & 31) >> 4) * 4 + ((D) & 3)) * 2))
    const int cwb0 = CWB(d0), cwb1 = CWB(d1), cwb2 = CWB(d2), cwb3 = CWB(d3);
#undef CWB
    const int xoff = lk * 128 + lr * 8;
    f16x8 bxT;
    bxT[0] = (_Float16)0.f; bxT[1] = (_Float16)0.f; bxT[2] = (_Float16)0.f; bxT[3] = (_Float16)0.f;
    bxT[4] = (lk == 0) ? (_Float16)1.0f : (_Float16)0.f;
    bxT[5] = (_Float16)0.f; bxT[6] = (_Float16)0.f; bxT[7] = (_Float16)0.f;
    const f32x4 CZ = {0.f, 0.f, 0.f, 0.f};
    __syncthreads();

// gates arrive prescaled: C0=log2e*i, C1=log2e*f, C2=2log2e*g, C3=log2e*o
#define CELL(J, HW) { \
    float ei_ = ex2(-C##J[0]), ef_ = ex2(-C##J[1]); \
    float eg_ = ex2(C##J[2]),  eo_ = ex2(-C##J[3]); \
    float di_ = 1.f + ei_, df_ = 1.f + ef_, dg_ = 1.f + eg_, dq_ = 1.f + eo_; \
    float r1_ = rcpf_(di_ * df_), r2_ = rcpf_(dq_ * dg_); \
    float si_ = r1_ * df_, sf_ = r1_ * di_, so_ = r2_ * dg_; \
    float tg_ = __builtin_fmaf(-2.f * r2_, dq_, 1.f); \
    cs##J = sf_ * cs##J + si_ * tg_; \
    float ec_ = ex2(cs##J * LOG2E2); \
    float th_ = __builtin_fmaf(-2.f, rcpf_(1.f + ec_), 1.f); \
    float hv_ = so_ * th_; \
    *(_Float16*)((char*)(HW) + cwb##J) = (_Float16)hv_; }

#define STEP(HR, HW, SI) { \
    const char* hrb_ = (const char*)(HR); \
    f16x8 bh0 = *(const f16x8*)(hrb_ + hro0); \
    f16x8 bh1 = *(const f16x8*)(hrb_ + hro1); \
    f16x8 bh2 = *(const f16x8*)(hrb_ + hro2); \
    f16x8 bh3 = *(const f16x8*)(hrb_ + hro3); \
    f16x8 bx = bxT; \
    *(f16x4*)&bx = *(const f16x4*)((const char*)xsh + (SI) * 512 + xoff); \
    f32x4 C0 = MFMA(ax0, bx, CZ); f32x4 C1 = MFMA(ax1, bx, CZ); \
    f32x4 C2 = MFMA(ax2, bx, CZ); f32x4 C3 = MFMA(ax3, bx, CZ); \
    C0 = MFMA(w0_0, bh0, C0); C1 = MFMA(w1_0, bh0, C1); \
    C2 = MFMA(w2_0, bh0, C2); C3 = MFMA(w3_0, bh0, C3); \
    C0 = MFMA(w0_1, bh1, C0); C1 = MFMA(w1_1, bh1, C1); \
    C2 = MFMA(w2_1, bh1, C2); C3 = MFMA(w3_1, bh1, C3); \
    C0 = MFMA(w0_2, bh2, C0); C1 = MFMA(w1_2, bh2, C1); \
    C2 = MFMA(w2_2, bh2, C2); C3 = MFMA(w3_2, bh2, C3); \
    C0 = MFMA(w0_3, bh3, C0); C1 = MFMA(w1_3, bh3, C1); \
    C2 = MFMA(w2_3, bh3, C2); C3 = MFMA(w3_3, bh3, C3); \
    CELL(0, HW) CELL(1, HW) CELL(2, HW) CELL(3, HW) \
    __syncthreads(); }

    for (int c = 0; c < 8; ++c) {
        {
            const int c0 = c * CHUNK;
            for (int i = t; i < 16 * CHUNK * 8; i += 512) {
                const int br  = i / (CHUNK * 8);
                const int rem = i - br * (CHUNK * 8);
                const int ti  = rem >> 3;
                const int dw  = rem & 7;
                const int s_  = c0 + ti;
                const int tt  = dir ? (TB - 1 - s_) : s_;
                float2 v = *(const float2*)(x + ((size_t)(b0 + br) * TB + tt) * NI + dw * 2);
                xsh[ti * 128 + (dw >> 1) * 32 + br * 2 + (dw & 1)] = packf16(v.x, v.y);
            }
        }
        __syncthreads();
        for (int si2 = 0; si2 < CHUNK / 2; ++si2) {
            STEP(hbuf0, hbuf1, si2 * 2)
            STEP(hbuf1, hbuf0, si2 * 2 + 1)
        }
    }
#undef STEP
#undef CELL

    {
        const size_t base = ((size_t)(b0 + lr) * 2 + dir) * 2 * NH;
#define FIN(J) { \
        float hv_ = (float)*(const _Float16*)((const char*)hbuf0 + cwb##J); \
        st[base + d##J] = hv_; st[base + NH + d##J] = cs##J; }
        FIN(0) FIN(1) FIN(2) FIN(3)
#undef FIN
    }
}

// named-var repetition macros
#define R8(F)  F(0)F(1)F(2)F(3)F(4)F(5)F(6)F(7)
#define R36_(F) F(8)F(9)F(10)F(11)F(12)F(13)F(14)F(15)F(16)F(17)F(18)F(19)F(20)F(21)F(22)F(23)F(24)F(25)F(26)F(27)F(28)F(29)F(30)F(31)F(32)F(33)F(34)F(35)
#define R36(F) R8(F) R36_(F)

#define QD(Q,i0,i1,i2,i3) { a0 = fdot2f((Q).x, w##i0, a0); a1 = fdot2f((Q).y, w##i1, a1); \
                            a2 = fdot2f((Q).z, w##i2, a2); a3 = fdot2f((Q).w, w##i3, a3); }
// weights from per-thread LDS uint4 (SQ) vs broadcast values (HQ)
#define QDS(HQ, SQ) { a0 = fdot2f((HQ).x, (SQ).x, a0); a1 = fdot2f((HQ).y, (SQ).y, a1); \
                      a2 = fdot2f((HQ).z, (SQ).z, a2); a3 = fdot2f((HQ).w, (SQ).w, a3); }

// ---------------- decoder (1024thr; 36 reg-dw + 36 LDS-dw weights, 3 barriers) ----------------
// Fixes R4-style scratch demotion: 72-dw rows exceeded the 64-VGPR cap at
// 1024thr -> reloads. Now 36 dw in regs + 9 uint4/thread in LDS (frag-major,
// conflict-free b128). Out-projection: wave w owns out[w] w/ static Wlin regs
// + shfl_xor reduce + direct global store (was prt/obuf + 2 extra barriers).
__global__ __launch_bounds__(1024, 1)
void dec_kernel(const float* __restrict__ x,
                const float* __restrict__ Wih_f, const float* __restrict__ Whh_f, const float* __restrict__ b_f,
                const float* __restrict__ Wih_b, const float* __restrict__ Whh_b, const float* __restrict__ b_b,
                const float* __restrict__ Wlin, const float* __restrict__ blin,
                const float* __restrict__ st, float* __restrict__ out)
{
    __shared__ unsigned int hFh[NH / 2], hBh[NH / 2];
    __shared__ unsigned int inpH[NI / 2];
    __shared__ float g[1024];
    __shared__ uint4 ws[9 * 1024];   // 147KB: per-thread weight tail + x-weights

    const int b    = blockIdx.x;
    const int t    = threadIdx.x;
    const int cell = t >> 9;
    const int r    = t & 511;
    const int w    = t >> 6;     // wave id = output index
    const int ln   = t & 63;

    const float* Wih = cell ? Wih_b : Wih_f;
    const float* Whh = cell ? Whh_b : Whh_f;
    const float* bv  = cell ? b_b   : b_f;

    // reg weights: h cols 0..71 (dwords 0..35)
#define DW(K) unsigned int w##K;
    R36(DW)
#undef DW
    {
        const float* hr = Whh + r * NH;
#define LH(K) w##K = packf16(hr[2*(K)], hr[2*(K)+1]);
        R36(LH)
#undef LH
        // LDS tail: h cols 72..127 (7 uint4) + x cols 0..15 (2 uint4)
        const float* xr = Wih + r * NI;
#pragma unroll
        for (int kk = 0; kk < 7; ++kk) {
            const float* pp = hr + 72 + kk * 8;
            uint4 q;
            q.x = packf16(pp[0], pp[1]); q.y = packf16(pp[2], pp[3]);
            q.z = packf16(pp[4], pp[5]); q.w = packf16(pp[6], pp[7]);
            ws[kk * 1024 + t] = q;
        }
        uint4 qa, qb;
        qa.x = packf16(xr[0], xr[1]);   qa.y = packf16(xr[2], xr[3]);
        qa.z = packf16(xr[4], xr[5]);   qa.w = packf16(xr[6], xr[7]);
        qb.x = packf16(xr[8], xr[9]);   qb.y = packf16(xr[10], xr[11]);
        qb.z = packf16(xr[12], xr[13]); qb.w = packf16(xr[14], xr[15]);
        ws[7 * 1024 + t] = qa;
        ws[8 * 1024 + t] = qb;
    }
    const float bias = bv[r];

    // out-projection statics: wave w, lane ln covers concat cols 4ln..4ln+3
    const float wl0 = Wlin[w * 256 + ln * 4 + 0];
    const float wl1 = Wlin[w * 256 + ln * 4 + 1];
    const float wl2 = Wlin[w * 256 + ln * 4 + 2];
    const float wl3 = Wlin[w * 256 + ln * 4 + 3];
    const float blw = blin[w];

    float cc = 0.0f;
    if (t < 64) {
        const float* sh = st + ((b * 2 + 0) * 2 + 0) * NH;
        hFh[t] = packf16(sh[2 * t], sh[2 * t + 1]);
    } else if (t < 128) {
        const float* sh = st + ((b * 2 + 1) * 2 + 0) * NH;
        hBh[t - 64] = packf16(sh[2 * (t - 64)], sh[2 * (t - 64) + 1]);
    }
    if (t < NH) cc = st[((b * 2 + 0) * 2 + 1) * NH + t];
    else if (t >= 512 && t < 512 + NH) cc = st[((b * 2 + 1) * 2 + 1) * NH + (t - 512)];
    if (t < 8) {
        float2 v = ((const float2*)(x + (size_t)b * TB * NI + (TB - 1) * NI))[t];
        inpH[t] = packf16(v.x, v.y);
    }
    __syncthreads();

    for (int s = 0; s < PRED; ++s) {
        // ---- P1: gates ----
        float a0 = bias, a1 = 0.f, a2 = 0.f, a3 = 0.f;
        uint4 q;
        const uint4* hv = cell ? (const uint4*)hBh : (const uint4*)hFh;
        q = hv[0]; QD(q, 0, 1, 2, 3)
        q = hv[1]; QD(q, 4, 5, 6, 7)
        q = hv[2]; QD(q, 8, 9, 10, 11)
        q = hv[3]; QD(q, 12, 13, 14, 15)
        q = hv[4]; QD(q, 16, 17, 18, 19)
        q = hv[5]; QD(q, 20, 21, 22, 23)
        q = hv[6]; QD(q, 24, 25, 26, 27)
        q = hv[7]; QD(q, 28, 29, 30, 31)
        q = hv[8]; QD(q, 32, 33, 34, 35)
#pragma unroll
        for (int kk = 0; kk < 7; ++kk) { QDS(hv[9 + kk], ws[kk * 1024 + t]) }
        {
            const uint4* xv = (const uint4*)inpH;
            QDS(xv[0], ws[7 * 1024 + t])
            QDS(xv[1], ws[8 * 1024 + t])
        }
        g[t] = (a0 + a1) + (a2 + a3);
        __syncthreads();

        // ---- P2: cell update ----
        if ((t < NH) || (t >= 512 && t < 512 + NH)) {
            float gi = g[t], gf = g[t + NH], gg = g[t + 2 * NH], go = g[t + 3 * NH];
            cc = sigf(gf) * cc + sigf(gi) * tanhf_(gg);
            float h = sigf(go) * tanhf_(cc);
            if (t < NH) ((_Float16*)hFh)[t] = (_Float16)h;
            else        ((_Float16*)hBh)[t - 512] = (_Float16)h;
        }
        __syncthreads();

        // ---- P3: out[w] = concat(hF,hB) . Wlin[w] + blin[w]; wave-reduce ----
        {
            const unsigned int* hsrc = (ln < 32) ? (hFh + 2 * ln) : (hBh + 2 * (ln - 32));
            uint2 hw = *(const uint2*)hsrc;
            float2 va = unpackf16(hw.x), vb = unpackf16(hw.y);
            float p = va.x * wl0 + va.y * wl1 + vb.x * wl2 + vb.y * wl3;
            p += __shfl_xor(p, 1);  p += __shfl_xor(p, 2);  p += __shfl_xor(p, 4);
            p += __shfl_xor(p, 8);  p += __shfl_xor(p, 16); p += __shfl_xor(p, 32);
            if (ln == 0) {
                float o = p + blw;
                out[(size_t)b * PRED * NI + s * NI + w] = o;
                ((_Float16*)inpH)[w] = (_Float16)o;
            }
        }
        __syncthreads();
    }
}

extern "C" void kernel_launch(void* const* d_in, const int* in_sizes, int n_in,
                              void* d_out, int out_size, void* d_ws, size_t ws_size,
                              hipStream_t stream)
{
    const float* x      = (const float*)d_in[0];
    const float* eWih_f = (const float*)d_in[1];
    const float* eWhh_f = (const float*)d_in[2];
    const float* eb_f   = (const float*)d_in[3];
    const float* eWih_b = (const float*)d_in[4];
    const float* eWhh_b = (const float*)d_in[5];
    const float* eb_b   = (const float*)d_in[6];
    const float* dWih_f = (const float*)d_in[7];
    const float* dWhh_f = (const float*)d_in[8];
    const float* db_f   = (const float*)d_in[9];
    const float* dWih_b = (const float*)d_in[10];
    const float* dWhh_b = (const float*)d_in[11];
    const float* db_b   = (const float*)d_in[12];
    const float* Wlin   = (const float*)d_in[13];
    const float* blin   = (const float*)d_in[14];

    float* st = (float*)d_ws;  // 256*2*2*128 f32 encoder final states

    enc_kernel<<<32, 512, 0, stream>>>(x, eWih_f, eWhh_f, eb_f, eWih_b, eWhh_b, eb_b, st);
    dec_kernel<<<256, 1024, 0, stream>>>(x, dWih_f, dWhh_f, db_f, dWih_b, dWhh_b, db_b,
                                         Wlin, blin, st, (float*)d_out);
}

// Round 15
// 804.081 us; speedup vs baseline: 1.0710x; 1.0710x over previous
//
#include <hip/hip_runtime.h>
#include <math.h>

#define TB    720
#define NI    16
#define NH    128
#define NG    512
#define PRED  96
#define CHUNK 90          // 720 = 8 * 90

typedef _Float16 h2    __attribute__((ext_vector_type(2)));
typedef _Float16 f16x4 __attribute__((ext_vector_type(4)));
typedef _Float16 f16x8 __attribute__((ext_vector_type(8)));
typedef float    f32x4 __attribute__((ext_vector_type(4)));

#define LOG2E  1.4426950408889634f
#define LOG2E2 2.8853900817779268f

__device__ __forceinline__ float rcpf_(float v) {
#if __has_builtin(__builtin_amdgcn_rcpf)
    return __builtin_amdgcn_rcpf(v);
#else
    return 1.0f / v;
#endif
}
__device__ __forceinline__ float ex2(float v) {
#if __has_builtin(__builtin_amdgcn_exp2f)
    return __builtin_amdgcn_exp2f(v);
#else
    return exp2f(v);
#endif
}
__device__ __forceinline__ float sigf(float v)   { return rcpf_(1.0f + __expf(-v)); }
__device__ __forceinline__ float tanhf_(float v) { return 1.0f - 2.0f * rcpf_(1.0f + __expf(2.0f * v)); }

__device__ __forceinline__ unsigned int packf16(float a, float b) {
    h2 p; p.x = (_Float16)a; p.y = (_Float16)b;
    return __builtin_bit_cast(unsigned int, p);
}
__device__ __forceinline__ float2 unpackf16(unsigned int u) {
    h2 p = __builtin_bit_cast(h2, u);
    return make_float2((float)p.x, (float)p.y);
}
__device__ __forceinline__ float fdot2f(unsigned int a, unsigned int b, float c) {
#if __has_builtin(__builtin_amdgcn_fdot2)
    return __builtin_amdgcn_fdot2(__builtin_bit_cast(h2, a), __builtin_bit_cast(h2, b), c, false);
#else
    h2 x = __builtin_bit_cast(h2, a), y = __builtin_bit_cast(h2, b);
    return c + (float)x.x * (float)y.x + (float)x.y * (float)y.y;
#endif
}

// A/B frag split-half k layout (verified R9-R14); scaled variant for exp2 gates
__device__ __forceinline__ f16x8 mk8s(const float* p, float s) {
    f16x8 v;
    v[0] = (_Float16)(p[0]  * s); v[1] = (_Float16)(p[1]  * s);
    v[2] = (_Float16)(p[2]  * s); v[3] = (_Float16)(p[3]  * s);
    v[4] = (_Float16)(p[16] * s); v[5] = (_Float16)(p[17] * s);
    v[6] = (_Float16)(p[18] * s); v[7] = (_Float16)(p[19] * s);
    return v;
}
__device__ __forceinline__ f32x4 MFMA(f16x8 a, f16x8 b, f32x4 c) {
    return __builtin_amdgcn_mfma_f32_16x16x32_f16(a, b, c, 0, 0, 0);
}

// ---------------- encoder (R14, unchanged: 611 us) ----------------
__global__ __launch_bounds__(512, 1)
void enc_kernel(const float* __restrict__ x,
                const float* __restrict__ Wih_f, const float* __restrict__ Whh_f, const float* __restrict__ b_f,
                const float* __restrict__ Wih_b, const float* __restrict__ Whh_b, const float* __restrict__ b_b,
                float* __restrict__ st)   // st[b][dir][{h,c}][NH]
{
    __shared__ _Float16 hbuf0[16 * NH];        // 4KB frag-major
    __shared__ _Float16 hbuf1[16 * NH];
    __shared__ unsigned int xsh[CHUNK * 128];  // 46KB

    const int blk = blockIdx.x;
    const int dir = blk & 1;
    const int b0  = (blk >> 1) << 4;
    const int t   = threadIdx.x;
    const int wv  = t >> 6;
    const int l   = t & 63;
    const int lr  = l & 15;
    const int lk  = l >> 4;

    const float* Wih = dir ? Wih_b : Wih_f;
    const float* Whh = dir ? Whh_b : Whh_f;
    const float* bv  = dir ? b_b   : b_f;

    const int mt0 = wv * 4, mt1 = wv * 4 + 1, mt2 = wv * 4 + 2, mt3 = wv * 4 + 3;
    const int R0 = mt0 * 16 + lr, R1 = mt1 * 16 + lr, R2 = mt2 * 16 + lr, R3 = mt3 * 16 + lr;
    const int or0 = (R0 & 3) * 128 + (R0 >> 2);
    const int or1 = (R1 & 3) * 128 + (R1 >> 2);
    const int or2 = (R2 & 3) * 128 + (R2 >> 2);
    const int or3 = (R3 & 3) * 128 + (R3 >> 2);
    const float s0 = ((or0 >> 7) == 2) ? LOG2E2 : LOG2E;
    const float s1 = ((or1 >> 7) == 2) ? LOG2E2 : LOG2E;
    const float s2 = ((or2 >> 7) == 2) ? LOG2E2 : LOG2E;
    const float s3 = ((or3 >> 7) == 2) ? LOG2E2 : LOG2E;
    const float* p0 = Whh + (size_t)or0 * NH + lk * 4;
    const float* p1 = Whh + (size_t)or1 * NH + lk * 4;
    const float* p2 = Whh + (size_t)or2 * NH + lk * 4;
    const float* p3 = Whh + (size_t)or3 * NH + lk * 4;
    f16x8 w0_0 = mk8s(p0, s0), w0_1 = mk8s(p0 + 32, s0), w0_2 = mk8s(p0 + 64, s0), w0_3 = mk8s(p0 + 96, s0);
    f16x8 w1_0 = mk8s(p1, s1), w1_1 = mk8s(p1 + 32, s1), w1_2 = mk8s(p1 + 64, s1), w1_3 = mk8s(p1 + 96, s1);
    f16x8 w2_0 = mk8s(p2, s2), w2_1 = mk8s(p2 + 32, s2), w2_2 = mk8s(p2 + 64, s2), w2_3 = mk8s(p2 + 96, s2);
    f16x8 w3_0 = mk8s(p3, s3), w3_1 = mk8s(p3 + 32, s3), w3_2 = mk8s(p3 + 64, s3), w3_3 = mk8s(p3 + 96, s3);

    f16x8 ax0, ax1, ax2, ax3;
#define MKAXR(DST, OR, SC) { \
    const float* xr_ = Wih + (size_t)(OR) * NI + lk * 4; \
    DST[0] = (_Float16)(xr_[0] * (SC)); DST[1] = (_Float16)(xr_[1] * (SC)); \
    DST[2] = (_Float16)(xr_[2] * (SC)); DST[3] = (_Float16)(xr_[3] * (SC)); \
    DST[4] = (_Float16)(bv[(OR)] * (SC)); \
    DST[5] = (_Float16)0.f; DST[6] = (_Float16)0.f; DST[7] = (_Float16)0.f; }
    MKAXR(ax0, or0, s0) MKAXR(ax1, or1, s1) MKAXR(ax2, or2, s2) MKAXR(ax3, or3, s3)
#undef MKAXR

    const int d0 = mt0 * 4 + lk, d1 = mt1 * 4 + lk, d2 = mt2 * 4 + lk, d3 = mt3 * 4 + lk;

    ((unsigned int*)hbuf0)[t] = 0u;
    ((unsigned int*)hbuf0)[t + 512] = 0u;
    float cs0 = 0.f, cs1 = 0.f, cs2 = 0.f, cs3 = 0.f;

    const int hro0 = 0 * 1024 + lk * 256 + lr * 16;
    const int hro1 = 1 * 1024 + lk * 256 + lr * 16;
    const int hro2 = 2 * 1024 + lk * 256 + lr * 16;
    const int hro3 = 3 * 1024 + lk * 256 + lr * 16;
#define CWB(D) ((((D) >> 5) * 1024) + ((((D) & 15) >> 2) * 256) + lr * 16 + (((((D) & 31) >> 4) * 4 + ((D) & 3)) * 2))
    const int cwb0 = CWB(d0), cwb1 = CWB(d1), cwb2 = CWB(d2), cwb3 = CWB(d3);
#undef CWB
    const int xoff = lk * 128 + lr * 8;
    f16x8 bxT;
    bxT[0] = (_Float16)0.f; bxT[1] = (_Float16)0.f; bxT[2] = (_Float16)0.f; bxT[3] = (_Float16)0.f;
    bxT[4] = (lk == 0) ? (_Float16)1.0f : (_Float16)0.f;
    bxT[5] = (_Float16)0.f; bxT[6] = (_Float16)0.f; bxT[7] = (_Float16)0.f;
    const f32x4 CZ = {0.f, 0.f, 0.f, 0.f};
    __syncthreads();

#define CELL(J, HW) { \
    float ei_ = ex2(-C##J[0]), ef_ = ex2(-C##J[1]); \
    float eg_ = ex2(C##J[2]),  eo_ = ex2(-C##J[3]); \
    float di_ = 1.f + ei_, df_ = 1.f + ef_, dg_ = 1.f + eg_, dq_ = 1.f + eo_; \
    float r1_ = rcpf_(di_ * df_), r2_ = rcpf_(dq_ * dg_); \
    float si_ = r1_ * df_, sf_ = r1_ * di_, so_ = r2_ * dg_; \
    float tg_ = __builtin_fmaf(-2.f * r2_, dq_, 1.f); \
    cs##J = sf_ * cs##J + si_ * tg_; \
    float ec_ = ex2(cs##J * LOG2E2); \
    float th_ = __builtin_fmaf(-2.f, rcpf_(1.f + ec_), 1.f); \
    float hv_ = so_ * th_; \
    *(_Float16*)((char*)(HW) + cwb##J) = (_Float16)hv_; }

#define STEP(HR, HW, SI) { \
    const char* hrb_ = (const char*)(HR); \
    f16x8 bh0 = *(const f16x8*)(hrb_ + hro0); \
    f16x8 bh1 = *(const f16x8*)(hrb_ + hro1); \
    f16x8 bh2 = *(const f16x8*)(hrb_ + hro2); \
    f16x8 bh3 = *(const f16x8*)(hrb_ + hro3); \
    f16x8 bx = bxT; \
    *(f16x4*)&bx = *(const f16x4*)((const char*)xsh + (SI) * 512 + xoff); \
    f32x4 C0 = MFMA(ax0, bx, CZ); f32x4 C1 = MFMA(ax1, bx, CZ); \
    f32x4 C2 = MFMA(ax2, bx, CZ); f32x4 C3 = MFMA(ax3, bx, CZ); \
    C0 = MFMA(w0_0, bh0, C0); C1 = MFMA(w1_0, bh0, C1); \
    C2 = MFMA(w2_0, bh0, C2); C3 = MFMA(w3_0, bh0, C3); \
    C0 = MFMA(w0_1, bh1, C0); C1 = MFMA(w1_1, bh1, C1); \
    C2 = MFMA(w2_1, bh1, C2); C3 = MFMA(w3_1, bh1, C3); \
    C0 = MFMA(w0_2, bh2, C0); C1 = MFMA(w1_2, bh2, C1); \
    C2 = MFMA(w2_2, bh2, C2); C3 = MFMA(w3_2, bh2, C3); \
    C0 = MFMA(w0_3, bh3, C0); C1 = MFMA(w1_3, bh3, C1); \
    C2 = MFMA(w2_3, bh3, C2); C3 = MFMA(w3_3, bh3, C3); \
    CELL(0, HW) CELL(1, HW) CELL(2, HW) CELL(3, HW) \
    __syncthreads(); }

    for (int c = 0; c < 8; ++c) {
        {
            const int c0 = c * CHUNK;
            for (int i = t; i < 16 * CHUNK * 8; i += 512) {
                const int br  = i / (CHUNK * 8);
                const int rem = i - br * (CHUNK * 8);
                const int ti  = rem >> 3;
                const int dw  = rem & 7;
                const int s_  = c0 + ti;
                const int tt  = dir ? (TB - 1 - s_) : s_;
                float2 v = *(const float2*)(x + ((size_t)(b0 + br) * TB + tt) * NI + dw * 2);
                xsh[ti * 128 + (dw >> 1) * 32 + br * 2 + (dw & 1)] = packf16(v.x, v.y);
            }
        }
        __syncthreads();
        for (int si2 = 0; si2 < CHUNK / 2; ++si2) {
            STEP(hbuf0, hbuf1, si2 * 2)
            STEP(hbuf1, hbuf0, si2 * 2 + 1)
        }
    }
#undef STEP
#undef CELL

    {
        const size_t base = ((size_t)(b0 + lr) * 2 + dir) * 2 * NH;
#define FIN(J) { \
        float hv_ = (float)*(const _Float16*)((const char*)hbuf0 + cwb##J); \
        st[base + d##J] = hv_; st[base + NH + d##J] = cs##J; }
        FIN(0) FIN(1) FIN(2) FIN(3)
#undef FIN
    }
}

// named-var repetition macros (arrays get scratch-demoted: R4/R6 evidence)
#define R8(F)  F(0)F(1)F(2)F(3)F(4)F(5)F(6)F(7)
#define R36_(F) F(8)F(9)F(10)F(11)F(12)F(13)F(14)F(15)F(16)F(17)F(18)F(19)F(20)F(21)F(22)F(23)F(24)F(25)F(26)F(27)F(28)F(29)F(30)F(31)F(32)F(33)F(34)F(35)
#define R36(F) R8(F) R36_(F)
#define R64(F) R36(F) F(36)F(37)F(38)F(39)F(40)F(41)F(42)F(43)F(44)F(45)F(46)F(47)F(48)F(49)F(50)F(51)F(52)F(53)F(54)F(55)F(56)F(57)F(58)F(59)F(60)F(61)F(62)F(63)

#define QD(Q,i0,i1,i2,i3) { a0 = fdot2f((Q).x, w##i0, a0); a1 = fdot2f((Q).y, w##i1, a1); \
                            a2 = fdot2f((Q).z, w##i2, a2); a3 = fdot2f((Q).w, w##i3, a3); }
#define QDU(Q,i0,i1,i2,i3) { a0 = fdot2f((Q).x, u##i0, a0); a1 = fdot2f((Q).y, u##i1, a1); \
                             a2 = fdot2f((Q).z, u##i2, a2); a3 = fdot2f((Q).w, u##i3, a3); }

// ---------------- decoder (R13 base + wave-reduce P3 into obuf; 3 barriers, no in-loop global) ----------------
__global__ __launch_bounds__(1024, 1)
void dec_kernel(const float* __restrict__ x,
                const float* __restrict__ Wih_f, const float* __restrict__ Whh_f, const float* __restrict__ b_f,
                const float* __restrict__ Wih_b, const float* __restrict__ Whh_b, const float* __restrict__ b_b,
                const float* __restrict__ Wlin, const float* __restrict__ blin,
                const float* __restrict__ st, float* __restrict__ out)
{
    __shared__ unsigned int hFh[NH / 2], hBh[NH / 2];
    __shared__ unsigned int inpH[NI / 2];
    __shared__ float g[1024];
    __shared__ float obuf[PRED * 16];    // 6KB output buffer, flushed once at end

    const int b    = blockIdx.x;
    const int t    = threadIdx.x;
    const int cell = t >> 9;
    const int r    = t & 511;
    const int w    = t >> 6;     // wave id = output index (16 waves, 16 outputs)
    const int ln   = t & 63;

    const float* Wih = cell ? Wih_b : Wih_f;
    const float* Whh = cell ? Whh_b : Whh_f;
    const float* bv  = cell ? b_b   : b_f;

#define DW(K) unsigned int w##K;
    R64(DW)
#undef DW
#define DU(K) unsigned int u##K;
    R8(DU)
#undef DU
    {
        const float* xr = Wih + r * NI;
        const float* hr = Whh + r * NH;
#define LU(K) u##K = packf16(xr[2*(K)], xr[2*(K)+1]);
        R8(LU)
#undef LU
#define LH(K) w##K = packf16(hr[2*(K)], hr[2*(K)+1]);
        R64(LH)
#undef LH
    }
    const float bias = bv[r];

    // out-projection statics: wave w, lane ln covers concat cols 4ln..4ln+3
    const float wl0 = Wlin[w * 256 + ln * 4 + 0];
    const float wl1 = Wlin[w * 256 + ln * 4 + 1];
    const float wl2 = Wlin[w * 256 + ln * 4 + 2];
    const float wl3 = Wlin[w * 256 + ln * 4 + 3];
    const float blw = blin[w];

    float cc = 0.0f;
    if (t < 64) {
        const float* sh = st + ((b * 2 + 0) * 2 + 0) * NH;
        hFh[t] = packf16(sh[2 * t], sh[2 * t + 1]);
    } else if (t < 128) {
        const float* sh = st + ((b * 2 + 1) * 2 + 0) * NH;
        hBh[t - 64] = packf16(sh[2 * (t - 64)], sh[2 * (t - 64) + 1]);
    }
    if (t < NH) cc = st[((b * 2 + 0) * 2 + 1) * NH + t];
    else if (t >= 512 && t < 512 + NH) cc = st[((b * 2 + 1) * 2 + 1) * NH + (t - 512)];
    if (t < 8) {
        float2 v = ((const float2*)(x + (size_t)b * TB * NI + (TB - 1) * NI))[t];
        inpH[t] = packf16(v.x, v.y);
    }
    __syncthreads();

    for (int s = 0; s < PRED; ++s) {
        // ---- P1: gates ----
        float a0 = bias, a1 = 0.f, a2 = 0.f, a3 = 0.f;
        uint4 q;
        {
            const uint4* xv = (const uint4*)inpH;
            q = xv[0]; QDU(q, 0, 1, 2, 3)
            q = xv[1]; QDU(q, 4, 5, 6, 7)
        }
        const uint4* hv = cell ? (const uint4*)hBh : (const uint4*)hFh;
        q = hv[0];  QD(q, 0, 1, 2, 3)
        q = hv[1];  QD(q, 4, 5, 6, 7)
        q = hv[2];  QD(q, 8, 9, 10, 11)
        q = hv[3];  QD(q, 12, 13, 14, 15)
        q = hv[4];  QD(q, 16, 17, 18, 19)
        q = hv[5];  QD(q, 20, 21, 22, 23)
        q = hv[6];  QD(q, 24, 25, 26, 27)
        q = hv[7];  QD(q, 28, 29, 30, 31)
        q = hv[8];  QD(q, 32, 33, 34, 35)
        q = hv[9];  QD(q, 36, 37, 38, 39)
        q = hv[10]; QD(q, 40, 41, 42, 43)
        q = hv[11]; QD(q, 44, 45, 46, 47)
        q = hv[12]; QD(q, 48, 49, 50, 51)
        q = hv[13]; QD(q, 52, 53, 54, 55)
        q = hv[14]; QD(q, 56, 57, 58, 59)
        q = hv[15]; QD(q, 60, 61, 62, 63)
        g[t] = (a0 + a1) + (a2 + a3);
        __syncthreads();

        // ---- P2: cell update ----
        if ((t < NH) || (t >= 512 && t < 512 + NH)) {
            float gi = g[t], gf = g[t + NH], gg = g[t + 2 * NH], go = g[t + 3 * NH];
            cc = sigf(gf) * cc + sigf(gi) * tanhf_(gg);
            float h = sigf(go) * tanhf_(cc);
            if (t < NH) ((_Float16*)hFh)[t] = (_Float16)h;
            else        ((_Float16*)hBh)[t - 512] = (_Float16)h;
        }
        __syncthreads();

        // ---- P3: out[w] = concat(hF,hB).Wlin[w] + blin[w]; wave shfl-reduce -> obuf
        {
            const unsigned int* hsrc = (ln < 32) ? (hFh + 2 * ln) : (hBh + 2 * (ln - 32));
            uint2 hw = *(const uint2*)hsrc;
            float2 va = unpackf16(hw.x), vb = unpackf16(hw.y);
            float p = va.x * wl0 + va.y * wl1 + vb.x * wl2 + vb.y * wl3;
            p += __shfl_xor(p, 1);  p += __shfl_xor(p, 2);  p += __shfl_xor(p, 4);
            p += __shfl_xor(p, 8);  p += __shfl_xor(p, 16); p += __shfl_xor(p, 32);
            if (ln == 0) {
                float o = p + blw;
                obuf[s * NI + w] = o;
                ((_Float16*)inpH)[w] = (_Float16)o;
            }
        }
        __syncthreads();
    }

    // flush outputs once (coalesced float4)
    {
        float4* dst = (float4*)(out + (size_t)b * PRED * NI);
        const float4* src = (const float4*)obuf;
        for (int i = t; i < PRED * NI / 4; i += 1024) dst[i] = src[i];
    }
}

extern "C" void kernel_launch(void* const* d_in, const int* in_sizes, int n_in,
                              void* d_out, int out_size, void* d_ws, size_t ws_size,
                              hipStream_t stream)
{
    const float* x      = (const float*)d_in[0];
    const float* eWih_f = (const float*)d_in[1];
    const float* eWhh_f = (const float*)d_in[2];
    const float* eb_f   = (const float*)d_in[3];
    const float* eWih_b = (const float*)d_in[4];
    const float* eWhh_b = (const float*)d_in[5];
    const float* eb_b   = (const float*)d_in[6];
    const float* dWih_f = (const float*)d_in[7];
    const float* dWhh_f = (const float*)d_in[8];
    const float* db_f   = (const float*)d_in[9];
    const float* dWih_b = (const float*)d_in[10];
    const float* dWhh_b = (const float*)d_in[11];
    const float* db_b   = (const float*)d_in[12];
    const float* Wlin   = (const float*)d_in[13];
    const float* blin   = (const float*)d_in[14];

    float* st = (float*)d_ws;  // 256*2*2*128 f32 encoder final states

    enc_kernel<<<32, 512, 0, stream>>>(x, eWih_f, eWhh_f, eb_f, eWih_b, eWhh_b, eb_b, st);
    dec_kernel<<<256, 1024, 0, stream>>>(x, dWih_f, dWhh_f, db_f, dWih_b, dWhh_b, db_b,
                                         Wlin, blin, st, (float*)d_out);
}

// Round 17
// 751.646 us; speedup vs baseline: 1.1457x; 1.0698x over previous
//
#include <hip/hip_runtime.h>
#include <math.h>

#define TB    720
#define NI    16
#define NH    128
#define NG    512
#define PRED  96
#define CHUNK 90          // 720 = 8 * 90

typedef _Float16 h2    __attribute__((ext_vector_type(2)));
typedef _Float16 f16x4 __attribute__((ext_vector_type(4)));
typedef _Float16 f16x8 __attribute__((ext_vector_type(8)));
typedef float    f32x4 __attribute__((ext_vector_type(4)));

#define LOG2E  1.4426950408889634f
#define LOG2E2 2.8853900817779268f

__device__ __forceinline__ float rcpf_(float v) {
#if __has_builtin(__builtin_amdgcn_rcpf)
    return __builtin_amdgcn_rcpf(v);
#else
    return 1.0f / v;
#endif
}
__device__ __forceinline__ float ex2(float v) {
#if __has_builtin(__builtin_amdgcn_exp2f)
    return __builtin_amdgcn_exp2f(v);
#else
    return exp2f(v);
#endif
}
__device__ __forceinline__ float sigf(float v)   { return rcpf_(1.0f + __expf(-v)); }
__device__ __forceinline__ float tanhf_(float v) { return 1.0f - 2.0f * rcpf_(1.0f + __expf(2.0f * v)); }

__device__ __forceinline__ unsigned int packf16(float a, float b) {
    h2 p; p.x = (_Float16)a; p.y = (_Float16)b;
    return __builtin_bit_cast(unsigned int, p);
}
__device__ __forceinline__ float2 unpackf16(unsigned int u) {
    h2 p = __builtin_bit_cast(h2, u);
    return make_float2((float)p.x, (float)p.y);
}
__device__ __forceinline__ float fdot2f(unsigned int a, unsigned int b, float c) {
#if __has_builtin(__builtin_amdgcn_fdot2)
    return __builtin_amdgcn_fdot2(__builtin_bit_cast(h2, a), __builtin_bit_cast(h2, b), c, false);
#else
    h2 x = __builtin_bit_cast(h2, a), y = __builtin_bit_cast(h2, b);
    return c + (float)x.x * (float)y.x + (float)x.y * (float)y.y;
#endif
}

// A/B frag split-half k layout (verified R9-R15); scaled variant for exp2 gates
__device__ __forceinline__ f16x8 mk8s(const float* p, float s) {
    f16x8 v;
    v[0] = (_Float16)(p[0]  * s); v[1] = (_Float16)(p[1]  * s);
    v[2] = (_Float16)(p[2]  * s); v[3] = (_Float16)(p[3]  * s);
    v[4] = (_Float16)(p[16] * s); v[5] = (_Float16)(p[17] * s);
    v[6] = (_Float16)(p[18] * s); v[7] = (_Float16)(p[19] * s);
    return v;
}
__device__ __forceinline__ f32x4 MFMA(f16x8 a, f16x8 b, f32x4 c) {
    return __builtin_amdgcn_mfma_f32_16x16x32_f16(a, b, c, 0, 0, 0);
}
// block LLVM from hoisting loop-invariant LDS reads (hoist->spill hazard, R10/R11-proven)
__device__ __forceinline__ int opaque(int v) { asm volatile("" : "+v"(v)); return v; }

// DPP wave64 reduce (VALU pipe, not LDS like __shfl). Ctrl/rmask MUST be
// compile-time constants for __builtin_amdgcn_update_dpp -> template params.
template <int CTRL, int RMASK>
__device__ __forceinline__ float dppadd(float v) {
    int s = __builtin_bit_cast(int, v);
    int d = __builtin_amdgcn_update_dpp(0, s, CTRL, RMASK, 0xf, true);
    return v + __builtin_bit_cast(float, d);
}

// ---------------- encoder (MFMA, 1024thr = 16 waves -> 4 waves/SIMD) ----------------
// grid 32 = (batch/16) x dir. Wave owns 2 m-tiles (wh frags 32 regs resident,
// fits the ~64-VGPR cap observed at 1024thr blocks). x-weights+bias in LDS
// frag-major (opaque offsets vs hoist->spill). 7 LDS reads/thread/step.
// R15 was latency-bound at 2 waves/SIMD (2040 cyc/step, all pipes <40%).
__global__ __launch_bounds__(1024, 4)
void enc_kernel(const float* __restrict__ x,
                const float* __restrict__ Wih_f, const float* __restrict__ Whh_f, const float* __restrict__ b_f,
                const float* __restrict__ Wih_b, const float* __restrict__ Whh_b, const float* __restrict__ b_b,
                float* __restrict__ st)   // st[b][dir][{h,c}][NH]
{
    __shared__ _Float16 hbuf0[16 * NH];        // 4KB frag-major
    __shared__ _Float16 hbuf1[16 * NH];
    __shared__ unsigned int xsh[CHUNK * 128];  // 46KB
    __shared__ uint4 axl[32 * 64];             // 32KB: x-weight frags [mt][lane]

    const int blk = blockIdx.x;
    const int dir = blk & 1;
    const int b0  = (blk >> 1) << 4;
    const int t   = threadIdx.x;
    const int wv  = t >> 6;      // 0..15
    const int l   = t & 63;
    const int lr  = l & 15;
    const int lk  = l >> 4;

    const float* Wih = dir ? Wih_b : Wih_f;
    const float* Whh = dir ? Whh_b : Whh_f;
    const float* bv  = dir ? b_b   : b_f;

    // stage x-weight frags (scaled, bias in elem4): 2048 entries, 2/thread
    for (int e = t; e < 2048; e += 1024) {
        const int mt = e >> 6, ll = e & 63;
        const int elr = ll & 15, elk = ll >> 4;
        const int R   = mt * 16 + elr;
        const int orr = (R & 3) * 128 + (R >> 2);
        const float sc = ((orr >> 7) == 2) ? LOG2E2 : LOG2E;
        const float* xr = Wih + (size_t)orr * NI + elk * 4;
        uint4 q;
        q.x = packf16(xr[0] * sc, xr[1] * sc);
        q.y = packf16(xr[2] * sc, xr[3] * sc);
        q.z = packf16(bv[orr] * sc, 0.f);   // elem4 = bias (pairs with bx[4]=1 @ lk==0)
        q.w = 0u;
        axl[mt * 64 + ll] = q;
    }

    // ---- resident Whh frags: 2 m-tiles x 4 frags = 32 VGPR ----
    const int mt0 = 2 * wv, mt1 = 2 * wv + 1;
    const int R0 = mt0 * 16 + lr, R1 = mt1 * 16 + lr;
    const int or0 = (R0 & 3) * 128 + (R0 >> 2);
    const int or1 = (R1 & 3) * 128 + (R1 >> 2);
    const float s0 = ((or0 >> 7) == 2) ? LOG2E2 : LOG2E;
    const float s1 = ((or1 >> 7) == 2) ? LOG2E2 : LOG2E;
    const float* p0 = Whh + (size_t)or0 * NH + lk * 4;
    const float* p1 = Whh + (size_t)or1 * NH + lk * 4;
    f16x8 w0_0 = mk8s(p0, s0), w0_1 = mk8s(p0 + 32, s0), w0_2 = mk8s(p0 + 64, s0), w0_3 = mk8s(p0 + 96, s0);
    f16x8 w1_0 = mk8s(p1, s1), w1_1 = mk8s(p1 + 32, s1), w1_2 = mk8s(p1 + 64, s1), w1_3 = mk8s(p1 + 96, s1);

    const int d0 = mt0 * 4 + lk, d1 = mt1 * 4 + lk;

    ((unsigned int*)hbuf0)[t] = 0u;   // 1024 dwords, one per thread
    float cs0 = 0.f, cs1 = 0.f;

    const int hro0 = 0 * 1024 + lk * 256 + lr * 16;
    const int hro1 = 1 * 1024 + lk * 256 + lr * 16;
    const int hro2 = 2 * 1024 + lk * 256 + lr * 16;
    const int hro3 = 3 * 1024 + lk * 256 + lr * 16;
#define CWB(D) ((((D) >> 5) * 1024) + ((((D) & 15) >> 2) * 256) + lr * 16 + (((((D) & 31) >> 4) * 4 + ((D) & 3)) * 2))
    const int cwb0 = CWB(d0), cwb1 = CWB(d1);
#undef CWB
    const int xoff = lk * 128 + lr * 8;
    const int axo0 = (mt0 * 64 + l) * 16;   // byte offsets into axl
    const int axo1 = (mt1 * 64 + l) * 16;
    const unsigned int oneku = (lk == 0) ? 0x00003c00u : 0u;  // f16 1.0 -> bx elem4
    const f32x4 CZ = {0.f, 0.f, 0.f, 0.f};
    __syncthreads();

#define CELL(J, HW) { \
    float ei_ = ex2(-C##J[0]), ef_ = ex2(-C##J[1]); \
    float eg_ = ex2(C##J[2]),  eo_ = ex2(-C##J[3]); \
    float di_ = 1.f + ei_, df_ = 1.f + ef_, dg_ = 1.f + eg_, dq_ = 1.f + eo_; \
    float r1_ = rcpf_(di_ * df_), r2_ = rcpf_(dq_ * dg_); \
    float si_ = r1_ * df_, sf_ = r1_ * di_, so_ = r2_ * dg_; \
    float tg_ = __builtin_fmaf(-2.f * r2_, dq_, 1.f); \
    cs##J = sf_ * cs##J + si_ * tg_; \
    float ec_ = ex2(cs##J * LOG2E2); \
    float th_ = __builtin_fmaf(-2.f, rcpf_(1.f + ec_), 1.f); \
    float hv_ = so_ * th_; \
    *(_Float16*)((char*)(HW) + cwb##J) = (_Float16)hv_; }

#define STEP(HR, HW, SI) { \
    const char* hrb_ = (const char*)(HR); \
    f16x8 bx; \
    { uint2 xq_ = *(const uint2*)((const char*)xsh + (SI) * 512 + xoff); \
      ((unsigned int*)&bx)[0] = xq_.x; ((unsigned int*)&bx)[1] = xq_.y; \
      ((unsigned int*)&bx)[2] = oneku; ((unsigned int*)&bx)[3] = 0u; } \
    f16x8 ax0_ = *(const f16x8*)((const char*)axl + opaque(axo0)); \
    f16x8 ax1_ = *(const f16x8*)((const char*)axl + opaque(axo1)); \
    f32x4 C0 = MFMA(ax0_, bx, CZ); \
    f32x4 C1 = MFMA(ax1_, bx, CZ); \
    f16x8 bh_; \
    bh_ = *(const f16x8*)(hrb_ + hro0); \
    C0 = MFMA(w0_0, bh_, C0); C1 = MFMA(w1_0, bh_, C1); \
    bh_ = *(const f16x8*)(hrb_ + hro1); \
    C0 = MFMA(w0_1, bh_, C0); C1 = MFMA(w1_1, bh_, C1); \
    bh_ = *(const f16x8*)(hrb_ + hro2); \
    C0 = MFMA(w0_2, bh_, C0); C1 = MFMA(w1_2, bh_, C1); \
    bh_ = *(const f16x8*)(hrb_ + hro3); \
    C0 = MFMA(w0_3, bh_, C0); C1 = MFMA(w1_3, bh_, C1); \
    CELL(0, HW) CELL(1, HW) \
    __syncthreads(); }

    for (int c = 0; c < 8; ++c) {
        {
            const int c0 = c * CHUNK;
            for (int i = t; i < 16 * CHUNK * 8; i += 1024) {
                const int br  = i / (CHUNK * 8);
                const int rem = i - br * (CHUNK * 8);
                const int ti  = rem >> 3;
                const int dw  = rem & 7;
                const int s_  = c0 + ti;
                const int tt  = dir ? (TB - 1 - s_) : s_;
                float2 v = *(const float2*)(x + ((size_t)(b0 + br) * TB + tt) * NI + dw * 2);
                xsh[ti * 128 + (dw >> 1) * 32 + br * 2 + (dw & 1)] = packf16(v.x, v.y);
            }
        }
        __syncthreads();
        for (int si2 = 0; si2 < CHUNK / 2; ++si2) {
            STEP(hbuf0, hbuf1, si2 * 2)
            STEP(hbuf1, hbuf0, si2 * 2 + 1)
        }
    }
#undef STEP
#undef CELL

    // final states: h in hbuf0 (720 even), c in regs
    {
        const size_t base = ((size_t)(b0 + lr) * 2 + dir) * 2 * NH;
#define FIN(J) { \
        float hv_ = (float)*(const _Float16*)((const char*)hbuf0 + cwb##J); \
        st[base + d##J] = hv_; st[base + NH + d##J] = cs##J; }
        FIN(0) FIN(1)
#undef FIN
    }
}

// named-var repetition macros (arrays get scratch-demoted: R4/R6 evidence)
#define R8(F)  F(0)F(1)F(2)F(3)F(4)F(5)F(6)F(7)
#define R36_(F) F(8)F(9)F(10)F(11)F(12)F(13)F(14)F(15)F(16)F(17)F(18)F(19)F(20)F(21)F(22)F(23)F(24)F(25)F(26)F(27)F(28)F(29)F(30)F(31)F(32)F(33)F(34)F(35)
#define R36(F) R8(F) R36_(F)
#define R64(F) R36(F) F(36)F(37)F(38)F(39)F(40)F(41)F(42)F(43)F(44)F(45)F(46)F(47)F(48)F(49)F(50)F(51)F(52)F(53)F(54)F(55)F(56)F(57)F(58)F(59)F(60)F(61)F(62)F(63)

#define QD(Q,i0,i1,i2,i3) { a0 = fdot2f((Q).x, w##i0, a0); a1 = fdot2f((Q).y, w##i1, a1); \
                            a2 = fdot2f((Q).z, w##i2, a2); a3 = fdot2f((Q).w, w##i3, a3); }
#define QDU(Q,i0,i1,i2,i3) { a0 = fdot2f((Q).x, u##i0, a0); a1 = fdot2f((Q).y, u##i1, a1); \
                             a2 = fdot2f((Q).z, u##i2, a2); a3 = fdot2f((Q).w, u##i3, a3); }

// ---------------- decoder (R15 + DPP wave-reduce instead of __shfl_xor) ----------------
__global__ __launch_bounds__(1024, 1)
void dec_kernel(const float* __restrict__ x,
                const float* __restrict__ Wih_f, const float* __restrict__ Whh_f, const float* __restrict__ b_f,
                const float* __restrict__ Wih_b, const float* __restrict__ Whh_b, const float* __restrict__ b_b,
                const float* __restrict__ Wlin, const float* __restrict__ blin,
                const float* __restrict__ st, float* __restrict__ out)
{
    __shared__ unsigned int hFh[NH / 2], hBh[NH / 2];
    __shared__ unsigned int inpH[NI / 2];
    __shared__ float g[1024];
    __shared__ float obuf[PRED * 16];    // 6KB output buffer, flushed once at end

    const int b    = blockIdx.x;
    const int t    = threadIdx.x;
    const int cell = t >> 9;
    const int r    = t & 511;
    const int w    = t >> 6;     // wave id = output index (16 waves, 16 outputs)
    const int ln   = t & 63;

    const float* Wih = cell ? Wih_b : Wih_f;
    const float* Whh = cell ? Whh_b : Whh_f;
    const float* bv  = cell ? b_b   : b_f;

#define DW(K) unsigned int w##K;
    R64(DW)
#undef DW
#define DU(K) unsigned int u##K;
    R8(DU)
#undef DU
    {
        const float* xr = Wih + r * NI;
        const float* hr = Whh + r * NH;
#define LU(K) u##K = packf16(xr[2*(K)], xr[2*(K)+1]);
        R8(LU)
#undef LU
#define LH(K) w##K = packf16(hr[2*(K)], hr[2*(K)+1]);
        R64(LH)
#undef LH
    }
    const float bias = bv[r];

    // out-projection statics: wave w, lane ln covers concat cols 4ln..4ln+3
    const float wl0 = Wlin[w * 256 + ln * 4 + 0];
    const float wl1 = Wlin[w * 256 + ln * 4 + 1];
    const float wl2 = Wlin[w * 256 + ln * 4 + 2];
    const float wl3 = Wlin[w * 256 + ln * 4 + 3];
    const float blw = blin[w];

    float cc = 0.0f;
    if (t < 64) {
        const float* sh = st + ((b * 2 + 0) * 2 + 0) * NH;
        hFh[t] = packf16(sh[2 * t], sh[2 * t + 1]);
    } else if (t < 128) {
        const float* sh = st + ((b * 2 + 1) * 2 + 0) * NH;
        hBh[t - 64] = packf16(sh[2 * (t - 64)], sh[2 * (t - 64) + 1]);
    }
    if (t < NH) cc = st[((b * 2 + 0) * 2 + 1) * NH + t];
    else if (t >= 512 && t < 512 + NH) cc = st[((b * 2 + 1) * 2 + 1) * NH + (t - 512)];
    if (t < 8) {
        float2 v = ((const float2*)(x + (size_t)b * TB * NI + (TB - 1) * NI))[t];
        inpH[t] = packf16(v.x, v.y);
    }
    __syncthreads();

    for (int s = 0; s < PRED; ++s) {
        // ---- P1: gates ----
        float a0 = bias, a1 = 0.f, a2 = 0.f, a3 = 0.f;
        uint4 q;
        {
            const uint4* xv = (const uint4*)inpH;
            q = xv[0]; QDU(q, 0, 1, 2, 3)
            q = xv[1]; QDU(q, 4, 5, 6, 7)
        }
        const uint4* hv = cell ? (const uint4*)hBh : (const uint4*)hFh;
        q = hv[0];  QD(q, 0, 1, 2, 3)
        q = hv[1];  QD(q, 4, 5, 6, 7)
        q = hv[2];  QD(q, 8, 9, 10, 11)
        q = hv[3];  QD(q, 12, 13, 14, 15)
        q = hv[4];  QD(q, 16, 17, 18, 19)
        q = hv[5];  QD(q, 20, 21, 22, 23)
        q = hv[6];  QD(q, 24, 25, 26, 27)
        q = hv[7];  QD(q, 28, 29, 30, 31)
        q = hv[8];  QD(q, 32, 33, 34, 35)
        q = hv[9];  QD(q, 36, 37, 38, 39)
        q = hv[10]; QD(q, 40, 41, 42, 43)
        q = hv[11]; QD(q, 44, 45, 46, 47)
        q = hv[12]; QD(q, 48, 49, 50, 51)
        q = hv[13]; QD(q, 52, 53, 54, 55)
        q = hv[14]; QD(q, 56, 57, 58, 59)
        q = hv[15]; QD(q, 60, 61, 62, 63)
        g[t] = (a0 + a1) + (a2 + a3);
        __syncthreads();

        // ---- P2: cell update ----
        if ((t < NH) || (t >= 512 && t < 512 + NH)) {
            float gi = g[t], gf = g[t + NH], gg = g[t + 2 * NH], go = g[t + 3 * NH];
            cc = sigf(gf) * cc + sigf(gi) * tanhf_(gg);
            float h = sigf(go) * tanhf_(cc);
            if (t < NH) ((_Float16*)hFh)[t] = (_Float16)h;
            else        ((_Float16*)hBh)[t - 512] = (_Float16)h;
        }
        __syncthreads();

        // ---- P3: out[w] = concat(hF,hB).Wlin[w] + blin[w]; DPP reduce -> lane 63
        {
            const unsigned int* hsrc = (ln < 32) ? (hFh + 2 * ln) : (hBh + 2 * (ln - 32));
            uint2 hw = *(const uint2*)hsrc;
            float2 va = unpackf16(hw.x), vb = unpackf16(hw.y);
            float p = va.x * wl0 + va.y * wl1 + vb.x * wl2 + vb.y * wl3;
            p = dppadd<0x111, 0xf>(p);   // row_shr:1
            p = dppadd<0x112, 0xf>(p);   // row_shr:2
            p = dppadd<0x114, 0xf>(p);   // row_shr:4
            p = dppadd<0x118, 0xf>(p);   // row_shr:8  -> lane 15/31/47/63 = row sums
            p = dppadd<0x142, 0xa>(p);   // row_bcast15 -> rows 1,3
            p = dppadd<0x143, 0xc>(p);   // row_bcast31 -> rows 2,3; total @ lane 63
            if (ln == 63) {
                float o = p + blw;
                obuf[s * NI + w] = o;
                ((_Float16*)inpH)[w] = (_Float16)o;
            }
        }
        __syncthreads();
    }

    // flush outputs once (coalesced float4)
    {
        float4* dst = (float4*)(out + (size_t)b * PRED * NI);
        const float4* src = (const float4*)obuf;
        for (int i = t; i < PRED * NI / 4; i += 1024) dst[i] = src[i];
    }
}

extern "C" void kernel_launch(void* const* d_in, const int* in_sizes, int n_in,
                              void* d_out, int out_size, void* d_ws, size_t ws_size,
                              hipStream_t stream)
{
    const float* x      = (const float*)d_in[0];
    const float* eWih_f = (const float*)d_in[1];
    const float* eWhh_f = (const float*)d_in[2];
    const float* eb_f   = (const float*)d_in[3];
    const float* eWih_b = (const float*)d_in[4];
    const float* eWhh_b = (const float*)d_in[5];
    const float* eb_b   = (const float*)d_in[6];
    const float* dWih_f = (const float*)d_in[7];
    const float* dWhh_f = (const float*)d_in[8];
    const float* db_f   = (const float*)d_in[9];
    const float* dWih_b = (const float*)d_in[10];
    const float* dWhh_b = (const float*)d_in[11];
    const float* db_b   = (const float*)d_in[12];
    const float* Wlin   = (const float*)d_in[13];
    const float* blin   = (const float*)d_in[14];

    float* st = (float*)d_ws;  // 256*2*2*128 f32 encoder final states

    enc_kernel<<<32, 1024, 0, stream>>>(x, eWih_f, eWhh_f, eb_f, eWih_b, eWhh_b, eb_b, st);
    dec_kernel<<<256, 1024, 0, stream>>>(x, dWih_f, dWhh_f, db_f, dWih_b, dWhh_b, db_b,
                                         Wlin, blin, st, (float*)d_out);
}

// Round 18
// 717.125 us; speedup vs baseline: 1.2009x; 1.0481x over previous
//
#include <hip/hip_runtime.h>
#include <math.h>

#define TB    720
#define NI    16
#define NH    128
#define NG    512
#define PRED  96
#define CHUNK 90          // 720 = 8 * 90

typedef _Float16 h2    __attribute__((ext_vector_type(2)));
typedef _Float16 f16x4 __attribute__((ext_vector_type(4)));
typedef _Float16 f16x8 __attribute__((ext_vector_type(8)));
typedef float    f32x4 __attribute__((ext_vector_type(4)));

#define LOG2E  1.4426950408889634f
#define LOG2E2 2.8853900817779268f

__device__ __forceinline__ float rcpf_(float v) {
#if __has_builtin(__builtin_amdgcn_rcpf)
    return __builtin_amdgcn_rcpf(v);
#else
    return 1.0f / v;
#endif
}
__device__ __forceinline__ float ex2(float v) {
#if __has_builtin(__builtin_amdgcn_exp2f)
    return __builtin_amdgcn_exp2f(v);
#else
    return exp2f(v);
#endif
}
__device__ __forceinline__ float sigf(float v)   { return rcpf_(1.0f + __expf(-v)); }
__device__ __forceinline__ float tanhf_(float v) { return 1.0f - 2.0f * rcpf_(1.0f + __expf(2.0f * v)); }

__device__ __forceinline__ unsigned int packf16(float a, float b) {
    h2 p; p.x = (_Float16)a; p.y = (_Float16)b;
    return __builtin_bit_cast(unsigned int, p);
}
__device__ __forceinline__ float2 unpackf16(unsigned int u) {
    h2 p = __builtin_bit_cast(h2, u);
    return make_float2((float)p.x, (float)p.y);
}
__device__ __forceinline__ float fdot2f(unsigned int a, unsigned int b, float c) {
#if __has_builtin(__builtin_amdgcn_fdot2)
    return __builtin_amdgcn_fdot2(__builtin_bit_cast(h2, a), __builtin_bit_cast(h2, b), c, false);
#else
    h2 x = __builtin_bit_cast(h2, a), y = __builtin_bit_cast(h2, b);
    return c + (float)x.x * (float)y.x + (float)x.y * (float)y.y;
#endif
}

// A/B frag split-half k layout (verified R9-R17); scaled variant for exp2 gates
__device__ __forceinline__ f16x8 mk8s(const float* p, float s) {
    f16x8 v;
    v[0] = (_Float16)(p[0]  * s); v[1] = (_Float16)(p[1]  * s);
    v[2] = (_Float16)(p[2]  * s); v[3] = (_Float16)(p[3]  * s);
    v[4] = (_Float16)(p[16] * s); v[5] = (_Float16)(p[17] * s);
    v[6] = (_Float16)(p[18] * s); v[7] = (_Float16)(p[19] * s);
    return v;
}
__device__ __forceinline__ f32x4 MFMA(f16x8 a, f16x8 b, f32x4 c) {
    return __builtin_amdgcn_mfma_f32_16x16x32_f16(a, b, c, 0, 0, 0);
}

// DPP wave64 reduce (VALU pipe, not LDS like __shfl). Ctrl/rmask are
// template params: __builtin_amdgcn_update_dpp requires literal constants.
template <int CTRL, int RMASK>
__device__ __forceinline__ float dppadd(float v) {
    int s = __builtin_bit_cast(int, v);
    int d = __builtin_amdgcn_update_dpp(0, s, CTRL, RMASK, 0xf, true);
    return v + __builtin_bit_cast(float, d);
}

// ---------------- encoder (MFMA, 1024thr, 5 LDS reads/thread/step) ----------------
// grid 32 = (batch/16) x dir; 16 waves, wave owns 2 m-tiles. ALL weights
// register-resident: 8 wh frags (32 VGPR) + 2 ax frags (8 VGPR, bias in
// elem4, ones-column via bx[4]). R17 was LDS-pipe-bound (7 reads/thread =
// ~1400 cyc/CU-step); dropping the axl LDS round-trip cuts to 5 reads.
// launch_bounds(1024,4) legally allows 128 VGPR -- R17's 52 had headroom.
__global__ __launch_bounds__(1024, 4)
void enc_kernel(const float* __restrict__ x,
                const float* __restrict__ Wih_f, const float* __restrict__ Whh_f, const float* __restrict__ b_f,
                const float* __restrict__ Wih_b, const float* __restrict__ Whh_b, const float* __restrict__ b_b,
                float* __restrict__ st)   // st[b][dir][{h,c}][NH]
{
    __shared__ _Float16 hbuf0[16 * NH];        // 4KB frag-major
    __shared__ _Float16 hbuf1[16 * NH];
    __shared__ unsigned int xsh[CHUNK * 128];  // 46KB

    const int blk = blockIdx.x;
    const int dir = blk & 1;
    const int b0  = (blk >> 1) << 4;
    const int t   = threadIdx.x;
    const int wv  = t >> 6;      // 0..15
    const int l   = t & 63;
    const int lr  = l & 15;
    const int lk  = l >> 4;

    const float* Wih = dir ? Wih_b : Wih_f;
    const float* Whh = dir ? Whh_b : Whh_f;
    const float* bv  = dir ? b_b   : b_f;

    // ---- resident Whh frags: 2 m-tiles x 4 frags = 32 VGPR ----
    const int mt0 = 2 * wv, mt1 = 2 * wv + 1;
    const int R0 = mt0 * 16 + lr, R1 = mt1 * 16 + lr;
    const int or0 = (R0 & 3) * 128 + (R0 >> 2);
    const int or1 = (R1 & 3) * 128 + (R1 >> 2);
    const float s0 = ((or0 >> 7) == 2) ? LOG2E2 : LOG2E;
    const float s1 = ((or1 >> 7) == 2) ? LOG2E2 : LOG2E;
    const float* p0 = Whh + (size_t)or0 * NH + lk * 4;
    const float* p1 = Whh + (size_t)or1 * NH + lk * 4;
    f16x8 w0_0 = mk8s(p0, s0), w0_1 = mk8s(p0 + 32, s0), w0_2 = mk8s(p0 + 64, s0), w0_3 = mk8s(p0 + 96, s0);
    f16x8 w1_0 = mk8s(p1, s1), w1_1 = mk8s(p1 + 32, s1), w1_2 = mk8s(p1 + 64, s1), w1_3 = mk8s(p1 + 96, s1);

    // ---- resident x-weight frags, bias at elem4 (k==16; pairs with bx[4]=1 @ lk==0)
    f16x8 ax0, ax1;
#define MKAXR(DST, OR, SC) { \
    const float* xr_ = Wih + (size_t)(OR) * NI + lk * 4; \
    DST[0] = (_Float16)(xr_[0] * (SC)); DST[1] = (_Float16)(xr_[1] * (SC)); \
    DST[2] = (_Float16)(xr_[2] * (SC)); DST[3] = (_Float16)(xr_[3] * (SC)); \
    DST[4] = (_Float16)(bv[(OR)] * (SC)); \
    DST[5] = (_Float16)0.f; DST[6] = (_Float16)0.f; DST[7] = (_Float16)0.f; }
    MKAXR(ax0, or0, s0) MKAXR(ax1, or1, s1)
#undef MKAXR

    const int d0 = mt0 * 4 + lk, d1 = mt1 * 4 + lk;

    ((unsigned int*)hbuf0)[t] = 0u;   // 1024 dwords, one per thread
    float cs0 = 0.f, cs1 = 0.f;

    const int hro0 = 0 * 1024 + lk * 256 + lr * 16;
    const int hro1 = 1 * 1024 + lk * 256 + lr * 16;
    const int hro2 = 2 * 1024 + lk * 256 + lr * 16;
    const int hro3 = 3 * 1024 + lk * 256 + lr * 16;
#define CWB(D) ((((D) >> 5) * 1024) + ((((D) & 15) >> 2) * 256) + lr * 16 + (((((D) & 31) >> 4) * 4 + ((D) & 3)) * 2))
    const int cwb0 = CWB(d0), cwb1 = CWB(d1);
#undef CWB
    const int xoff = lk * 128 + lr * 8;
    const unsigned int oneku = (lk == 0) ? 0x00003c00u : 0u;  // f16 1.0 -> bx elem4
    const f32x4 CZ = {0.f, 0.f, 0.f, 0.f};
    __syncthreads();

#define CELL(J, HW) { \
    float ei_ = ex2(-C##J[0]), ef_ = ex2(-C##J[1]); \
    float eg_ = ex2(C##J[2]),  eo_ = ex2(-C##J[3]); \
    float di_ = 1.f + ei_, df_ = 1.f + ef_, dg_ = 1.f + eg_, dq_ = 1.f + eo_; \
    float r1_ = rcpf_(di_ * df_), r2_ = rcpf_(dq_ * dg_); \
    float si_ = r1_ * df_, sf_ = r1_ * di_, so_ = r2_ * dg_; \
    float tg_ = __builtin_fmaf(-2.f * r2_, dq_, 1.f); \
    cs##J = sf_ * cs##J + si_ * tg_; \
    float ec_ = ex2(cs##J * LOG2E2); \
    float th_ = __builtin_fmaf(-2.f, rcpf_(1.f + ec_), 1.f); \
    float hv_ = so_ * th_; \
    *(_Float16*)((char*)(HW) + cwb##J) = (_Float16)hv_; }

#define STEP(HR, HW, SI) { \
    const char* hrb_ = (const char*)(HR); \
    f16x8 bx; \
    { uint2 xq_ = *(const uint2*)((const char*)xsh + (SI) * 512 + xoff); \
      ((unsigned int*)&bx)[0] = xq_.x; ((unsigned int*)&bx)[1] = xq_.y; \
      ((unsigned int*)&bx)[2] = oneku; ((unsigned int*)&bx)[3] = 0u; } \
    f32x4 C0 = MFMA(ax0, bx, CZ); \
    f32x4 C1 = MFMA(ax1, bx, CZ); \
    f16x8 bh_; \
    bh_ = *(const f16x8*)(hrb_ + hro0); \
    C0 = MFMA(w0_0, bh_, C0); C1 = MFMA(w1_0, bh_, C1); \
    bh_ = *(const f16x8*)(hrb_ + hro1); \
    C0 = MFMA(w0_1, bh_, C0); C1 = MFMA(w1_1, bh_, C1); \
    bh_ = *(const f16x8*)(hrb_ + hro2); \
    C0 = MFMA(w0_2, bh_, C0); C1 = MFMA(w1_2, bh_, C1); \
    bh_ = *(const f16x8*)(hrb_ + hro3); \
    C0 = MFMA(w0_3, bh_, C0); C1 = MFMA(w1_3, bh_, C1); \
    CELL(0, HW) CELL(1, HW) \
    __syncthreads(); }

    for (int c = 0; c < 8; ++c) {
        {
            const int c0 = c * CHUNK;
            for (int i = t; i < 16 * CHUNK * 8; i += 1024) {
                const int br  = i / (CHUNK * 8);
                const int rem = i - br * (CHUNK * 8);
                const int ti  = rem >> 3;
                const int dw  = rem & 7;
                const int s_  = c0 + ti;
                const int tt  = dir ? (TB - 1 - s_) : s_;
                float2 v = *(const float2*)(x + ((size_t)(b0 + br) * TB + tt) * NI + dw * 2);
                xsh[ti * 128 + (dw >> 1) * 32 + br * 2 + (dw & 1)] = packf16(v.x, v.y);
            }
        }
        __syncthreads();
        for (int si2 = 0; si2 < CHUNK / 2; ++si2) {
            STEP(hbuf0, hbuf1, si2 * 2)
            STEP(hbuf1, hbuf0, si2 * 2 + 1)
        }
    }
#undef STEP
#undef CELL

    // final states: h in hbuf0 (720 even), c in regs
    {
        const size_t base = ((size_t)(b0 + lr) * 2 + dir) * 2 * NH;
#define FIN(J) { \
        float hv_ = (float)*(const _Float16*)((const char*)hbuf0 + cwb##J); \
        st[base + d##J] = hv_; st[base + NH + d##J] = cs##J; }
        FIN(0) FIN(1)
#undef FIN
    }
}

// named-var repetition macros (arrays get scratch-demoted: R4/R6 evidence)
#define R8(F)  F(0)F(1)F(2)F(3)F(4)F(5)F(6)F(7)
#define R36_(F) F(8)F(9)F(10)F(11)F(12)F(13)F(14)F(15)F(16)F(17)F(18)F(19)F(20)F(21)F(22)F(23)F(24)F(25)F(26)F(27)F(28)F(29)F(30)F(31)F(32)F(33)F(34)F(35)
#define R36(F) R8(F) R36_(F)
#define R64(F) R36(F) F(36)F(37)F(38)F(39)F(40)F(41)F(42)F(43)F(44)F(45)F(46)F(47)F(48)F(49)F(50)F(51)F(52)F(53)F(54)F(55)F(56)F(57)F(58)F(59)F(60)F(61)F(62)F(63)

#define QD(Q,i0,i1,i2,i3) { a0 = fdot2f((Q).x, w##i0, a0); a1 = fdot2f((Q).y, w##i1, a1); \
                            a2 = fdot2f((Q).z, w##i2, a2); a3 = fdot2f((Q).w, w##i3, a3); }
#define QDU(Q,i0,i1,i2,i3) { a0 = fdot2f((Q).x, u##i0, a0); a1 = fdot2f((Q).y, u##i1, a1); \
                             a2 = fdot2f((Q).z, u##i2, a2); a3 = fdot2f((Q).w, u##i3, a3); }

// ---------------- decoder (R17: DPP wave-reduce, obuf flush; unchanged) ----------------
__global__ __launch_bounds__(1024, 1)
void dec_kernel(const float* __restrict__ x,
                const float* __restrict__ Wih_f, const float* __restrict__ Whh_f, const float* __restrict__ b_f,
                const float* __restrict__ Wih_b, const float* __restrict__ Whh_b, const float* __restrict__ b_b,
                const float* __restrict__ Wlin, const float* __restrict__ blin,
                const float* __restrict__ st, float* __restrict__ out)
{
    __shared__ unsigned int hFh[NH / 2], hBh[NH / 2];
    __shared__ unsigned int inpH[NI / 2];
    __shared__ float g[1024];
    __shared__ float obuf[PRED * 16];    // 6KB output buffer, flushed once at end

    const int b    = blockIdx.x;
    const int t    = threadIdx.x;
    const int cell = t >> 9;
    const int r    = t & 511;
    const int w    = t >> 6;     // wave id = output index (16 waves, 16 outputs)
    const int ln   = t & 63;

    const float* Wih = cell ? Wih_b : Wih_f;
    const float* Whh = cell ? Whh_b : Whh_f;
    const float* bv  = cell ? b_b   : b_f;

#define DW(K) unsigned int w##K;
    R64(DW)
#undef DW
#define DU(K) unsigned int u##K;
    R8(DU)
#undef DU
    {
        const float* xr = Wih + r * NI;
        const float* hr = Whh + r * NH;
#define LU(K) u##K = packf16(xr[2*(K)], xr[2*(K)+1]);
        R8(LU)
#undef LU
#define LH(K) w##K = packf16(hr[2*(K)], hr[2*(K)+1]);
        R64(LH)
#undef LH
    }
    const float bias = bv[r];

    // out-projection statics: wave w, lane ln covers concat cols 4ln..4ln+3
    const float wl0 = Wlin[w * 256 + ln * 4 + 0];
    const float wl1 = Wlin[w * 256 + ln * 4 + 1];
    const float wl2 = Wlin[w * 256 + ln * 4 + 2];
    const float wl3 = Wlin[w * 256 + ln * 4 + 3];
    const float blw = blin[w];

    float cc = 0.0f;
    if (t < 64) {
        const float* sh = st + ((b * 2 + 0) * 2 + 0) * NH;
        hFh[t] = packf16(sh[2 * t], sh[2 * t + 1]);
    } else if (t < 128) {
        const float* sh = st + ((b * 2 + 1) * 2 + 0) * NH;
        hBh[t - 64] = packf16(sh[2 * (t - 64)], sh[2 * (t - 64) + 1]);
    }
    if (t < NH) cc = st[((b * 2 + 0) * 2 + 1) * NH + t];
    else if (t >= 512 && t < 512 + NH) cc = st[((b * 2 + 1) * 2 + 1) * NH + (t - 512)];
    if (t < 8) {
        float2 v = ((const float2*)(x + (size_t)b * TB * NI + (TB - 1) * NI))[t];
        inpH[t] = packf16(v.x, v.y);
    }
    __syncthreads();

    for (int s = 0; s < PRED; ++s) {
        // ---- P1: gates ----
        float a0 = bias, a1 = 0.f, a2 = 0.f, a3 = 0.f;
        uint4 q;
        {
            const uint4* xv = (const uint4*)inpH;
            q = xv[0]; QDU(q, 0, 1, 2, 3)
            q = xv[1]; QDU(q, 4, 5, 6, 7)
        }
        const uint4* hv = cell ? (const uint4*)hBh : (const uint4*)hFh;
        q = hv[0];  QD(q, 0, 1, 2, 3)
        q = hv[1];  QD(q, 4, 5, 6, 7)
        q = hv[2];  QD(q, 8, 9, 10, 11)
        q = hv[3];  QD(q, 12, 13, 14, 15)
        q = hv[4];  QD(q, 16, 17, 18, 19)
        q = hv[5];  QD(q, 20, 21, 22, 23)
        q = hv[6];  QD(q, 24, 25, 26, 27)
        q = hv[7];  QD(q, 28, 29, 30, 31)
        q = hv[8];  QD(q, 32, 33, 34, 35)
        q = hv[9];  QD(q, 36, 37, 38, 39)
        q = hv[10]; QD(q, 40, 41, 42, 43)
        q = hv[11]; QD(q, 44, 45, 46, 47)
        q = hv[12]; QD(q, 48, 49, 50, 51)
        q = hv[13]; QD(q, 52, 53, 54, 55)
        q = hv[14]; QD(q, 56, 57, 58, 59)
        q = hv[15]; QD(q, 60, 61, 62, 63)
        g[t] = (a0 + a1) + (a2 + a3);
        __syncthreads();

        // ---- P2: cell update ----
        if ((t < NH) || (t >= 512 && t < 512 + NH)) {
            float gi = g[t], gf = g[t + NH], gg = g[t + 2 * NH], go = g[t + 3 * NH];
            cc = sigf(gf) * cc + sigf(gi) * tanhf_(gg);
            float h = sigf(go) * tanhf_(cc);
            if (t < NH) ((_Float16*)hFh)[t] = (_Float16)h;
            else        ((_Float16*)hBh)[t - 512] = (_Float16)h;
        }
        __syncthreads();

        // ---- P3: out[w] = concat(hF,hB).Wlin[w] + blin[w]; DPP reduce -> lane 63
        {
            const unsigned int* hsrc = (ln < 32) ? (hFh + 2 * ln) : (hBh + 2 * (ln - 32));
            uint2 hw = *(const uint2*)hsrc;
            float2 va = unpackf16(hw.x), vb = unpackf16(hw.y);
            float p = va.x * wl0 + va.y * wl1 + vb.x * wl2 + vb.y * wl3;
            p = dppadd<0x111, 0xf>(p);   // row_shr:1
            p = dppadd<0x112, 0xf>(p);   // row_shr:2
            p = dppadd<0x114, 0xf>(p);   // row_shr:4
            p = dppadd<0x118, 0xf>(p);   // row_shr:8  -> lane 15/31/47/63 = row sums
            p = dppadd<0x142, 0xa>(p);   // row_bcast15 -> rows 1,3
            p = dppadd<0x143, 0xc>(p);   // row_bcast31 -> rows 2,3; total @ lane 63
            if (ln == 63) {
                float o = p + blw;
                obuf[s * NI + w] = o;
                ((_Float16*)inpH)[w] = (_Float16)o;
            }
        }
        __syncthreads();
    }

    // flush outputs once (coalesced float4)
    {
        float4* dst = (float4*)(out + (size_t)b * PRED * NI);
        const float4* src = (const float4*)obuf;
        for (int i = t; i < PRED * NI / 4; i += 1024) dst[i] = src[i];
    }
}

extern "C" void kernel_launch(void* const* d_in, const int* in_sizes, int n_in,
                              void* d_out, int out_size, void* d_ws, size_t ws_size,
                              hipStream_t stream)
{
    const float* x      = (const float*)d_in[0];
    const float* eWih_f = (const float*)d_in[1];
    const float* eWhh_f = (const float*)d_in[2];
    const float* eb_f   = (const float*)d_in[3];
    const float* eWih_b = (const float*)d_in[4];
    const float* eWhh_b = (const float*)d_in[5];
    const float* eb_b   = (const float*)d_in[6];
    const float* dWih_f = (const float*)d_in[7];
    const float* dWhh_f = (const float*)d_in[8];
    const float* db_f   = (const float*)d_in[9];
    const float* dWih_b = (const float*)d_in[10];
    const float* dWhh_b = (const float*)d_in[11];
    const float* db_b   = (const float*)d_in[12];
    const float* Wlin   = (const float*)d_in[13];
    const float* blin   = (const float*)d_in[14];

    float* st = (float*)d_ws;  // 256*2*2*128 f32 encoder final states

    enc_kernel<<<32, 1024, 0, stream>>>(x, eWih_f, eWhh_f, eb_f, eWih_b, eWhh_b, eb_b, st);
    dec_kernel<<<256, 1024, 0, stream>>>(x, dWih_f, dWhh_f, db_f, dWih_b, dWhh_b, db_b,
                                         Wlin, blin, st, (float*)d_out);
}